// Round 5
// baseline (25.909 us; speedup 1.0000x reference)
//
#include <hip/hip_runtime.h>

#define MAX_NODE 511
#define SLOTS (MAX_NODE + 1)   // 512
#define CDIM 1024              // channels (f32)
#define CPR  (CDIM / 4)        // 256 float4 per row
#define ITER 8                 // float4 elements per thread
#define THREADS 256

typedef float f32x4 __attribute__((ext_vector_type(4)));

// Persistent grid-stride copy kernel. Per-block: wave 0 builds the exclusive
// prefix of nn into LDS once; main loop moves ITER float4s per thread with all
// addressing from LDS broadcasts (no dependent scalar chain between bursts).
__global__ __launch_bounds__(THREADS)
void graph_embed_kernel(const float* __restrict__ patch,   // [total_nodes, CDIM]
                        const float* __restrict__ cent,    // [total_nodes, 2]
                        const float* __restrict__ img,     // [B, CDIM]
                        const int*   __restrict__ nn,      // [B]
                        float* __restrict__ out, int B) {
    __shared__ int s_off[64];
    __shared__ int s_n[64];

    const int t    = threadIdx.x;
    const int lane = t & 63;

    if (t < 64) {
        int v = (lane < B) ? nn[lane] : 0;
        int inc = v;
        #pragma unroll
        for (int d = 1; d < 64; d <<= 1) {
            int o = __shfl_up(inc, d, 64);
            if (lane >= d) inc += o;
        }
        s_off[lane] = inc - v;   // exclusive prefix
        s_n[lane]   = v;
    }
    __syncthreads();

    float* features = out;
    float* mask     = out + (size_t)B * SLOTS * CDIM;
    float* pos_x    = mask  + (size_t)B * SLOTS;
    float* pos_y    = pos_x + (size_t)B * SLOTS;

    const f32x4* patch4 = reinterpret_cast<const f32x4*>(patch);
    const f32x4* img4   = reinterpret_cast<const f32x4*>(img);
    f32x4*       feat4  = reinterpret_cast<f32x4*>(features);

    const size_t total  = (size_t)B * SLOTS * CPR;
    const size_t g0     = (size_t)blockIdx.x * THREADS + t;
    const size_t stride = (size_t)gridDim.x * THREADS;

    f32x4 r[ITER];
    #pragma unroll
    for (int i = 0; i < ITER; ++i) {
        const size_t e = g0 + (size_t)i * stride;
        if (e < total) {
            const int row  = (int)(e >> 8);      // / CPR
            const int col  = (int)(e & (CPR - 1));
            const int b    = row >> 9;           // / SLOTS
            const int slot = row & (SLOTS - 1);
            const int n    = s_n[b];
            const int off  = s_off[b];
            const int n_eff = (n < MAX_NODE) ? n : MAX_NODE;
            f32x4 v;
            if (slot == 0) {
                v = img4[(size_t)b * CPR + col];
            } else if (slot - 1 < n_eff) {
                v = patch4[(size_t)(off + slot - 1) * CPR + col];
            } else {
                v = (f32x4)(0.f);
            }
            r[i] = v;
        }
    }
    #pragma unroll
    for (int i = 0; i < ITER; ++i) {
        const size_t e = g0 + (size_t)i * stride;
        if (e < total) feat4[e] = r[i];
    }

    // mask / pos tail: first B*SLOTS global threads, one row each.
    if (g0 < (size_t)B * SLOTS) {
        const int row  = (int)g0;
        const int b    = row >> 9;
        const int slot = row & (SLOTS - 1);
        const int n    = s_n[b];
        const int off  = s_off[b];
        const int n_eff = (n < MAX_NODE) ? n : MAX_NODE;
        const float m = (slot >= n + 1 && n <= MAX_NODE) ? 1.0f : 0.0f;
        float px = 0.f, py = 0.f;
        if (slot >= 1 && slot - 1 < n_eff) {
            px = cent[(size_t)(off + slot - 1) * 2 + 0];
            py = cent[(size_t)(off + slot - 1) * 2 + 1];
        }
        mask[g0]  = m;
        pos_x[g0] = px;
        pos_y[g0] = py;
    }
}

extern "C" void kernel_launch(void* const* d_in, const int* in_sizes, int n_in,
                              void* d_out, int out_size, void* d_ws, size_t ws_size,
                              hipStream_t stream) {
    const float* patch = (const float*)d_in[0];   // [total_nodes, 1024]
    const float* cent  = (const float*)d_in[1];   // [total_nodes, 2]
    const float* img   = (const float*)d_in[2];   // [B, 1024]
    const int*   nn    = (const int*)d_in[3];     // [B]
    float* out = (float*)d_out;

    const int B = in_sizes[3];
    const size_t total = (size_t)B * SLOTS * CPR;          // float4 elements
    const int nblocks = (int)((total + (size_t)THREADS * ITER - 1) / ((size_t)THREADS * ITER));
    graph_embed_kernel<<<nblocks, THREADS, 0, stream>>>(patch, cent, img, nn, out, B);
}